// Round 16
// baseline (229.451 us; speedup 1.0000x reference)
//
#include <hip/hip_runtime.h>
#include <hip/hip_bf16.h>

// SDPA B=2 H=16 S=2048 D=64, outputs (out, attn) f32.
// R16 = R11 (168.5us best) with ONE change: attn stores are PLAIN (cached)
// instead of nontemporal. R11's transposed pattern writes complete aligned
// 128B lines per instruction segment -> L2 should allocate-without-fetch
// (no RFO, unlike R7's 64B half-line plain stores) and drain to HBM at the
// fill-kernel rate (~6.7 TB/s), absorbing compute/store burstiness.
// Everything else byte-identical to R11: two-pass flash, QT=128, 8 waves x
// 16 rows, 64-col chunks, 2D grid (x=qtile, y=bh); swapped QK^T; K=16 PV
// (B-frag IS the lane's p-quad); full-line store transpose via 32KB shPT;
// fixed-C softmax (C=0); Q pre-scaled 1/8; out epilogue stays nt
// (quarter-line scattered -> plain would RFO).

#define S_LEN 2048
#define DH 64
#define QT 128
#define NCH (S_LEN / 64)

typedef __attribute__((ext_vector_type(8))) short  s16x8;
typedef __attribute__((ext_vector_type(4))) short  s16x4;
typedef __attribute__((ext_vector_type(8))) __bf16 bf16x8;
typedef __attribute__((ext_vector_type(4))) float  f32x4;
typedef __attribute__((ext_vector_type(2))) unsigned int u32x2;

__device__ __forceinline__ short f2bf(float x) {
    __hip_bfloat16 h = __float2bfloat16(x);   // RNE
    return *reinterpret_cast<short*>(&h);
}
__device__ __forceinline__ unsigned pack2(float a, float b) {
    return (unsigned)(unsigned short)f2bf(a) | ((unsigned)(unsigned short)f2bf(b) << 16);
}
__device__ __forceinline__ bf16x8 ldfrag(const short* p) {
    s16x8 t = *(const s16x8*)p;               // ds_read_b128
    return __builtin_bit_cast(bf16x8, t);
}
// XOR swizzles (G4): [rows][64] tiles.
__device__ __forceinline__ int SW (int r, int c) { return r * 64 + (c ^ ((r & 7) << 3)); }
__device__ __forceinline__ int SWF(int r, int c) { return r * 64 + (c ^ ((r & 7) << 3)); }

__global__ __launch_bounds__(512, 4) void sdpa_kernel(
    const float* __restrict__ q, const float* __restrict__ k,
    const float* __restrict__ v, const int* __restrict__ mask,
    float* __restrict__ out, float* __restrict__ attn)
{
    __shared__ __align__(16) short shK[2][64 * 64];    // 16 KB dbuf [key][d]
    __shared__ __align__(16) short shVt[2][64 * 64];   // 16 KB dbuf [d][key]
    __shared__ __align__(16) float shPT[8][16 * 64];   // 32 KB, per-wave P f32
    __shared__ char shMask[S_LEN];                     // 2 KB

    const int tid  = threadIdx.x;
    const int lane = tid & 63;
    const int w    = tid >> 6;    // 0..7, owns q rows w*16..w*16+15
    const int l15  = lane & 15;   // q row within wave band
    const int lg   = lane >> 4;   // 0..3

    const int bh = blockIdx.y;    // 0..31
    const int q0 = blockIdx.x * QT;
    const int b  = bh >> 4;

    const float* qbase = q + ((size_t)bh * S_LEN + q0) * DH;
    const float* kbase = k + (size_t)bh * S_LEN * DH;
    const float* vbase = v + (size_t)bh * S_LEN * DH;
    float* attnbh = attn + (size_t)bh * S_LEN * S_LEN;

    // ---- mask bytes to LDS ----
    for (int i = tid; i < S_LEN; i += 512)
        shMask[i] = (char)(mask[b * S_LEN + i] != 0);

    // ---- Q fragments straight to registers (scaled 1/8, bf16) ----
    const int qrow = w * 16 + l15;
    bf16x8 qf0, qf1;
    {
        const float* qp = qbase + qrow * DH + 8 * lg;
        const float4 a0 = *(const float4*)(qp);
        const float4 a1 = *(const float4*)(qp + 4);
        const float4 b0 = *(const float4*)(qp + 32);
        const float4 b1 = *(const float4*)(qp + 36);
        s16x8 t0, t1;
        t0[0]=f2bf(a0.x*0.125f); t0[1]=f2bf(a0.y*0.125f); t0[2]=f2bf(a0.z*0.125f); t0[3]=f2bf(a0.w*0.125f);
        t0[4]=f2bf(a1.x*0.125f); t0[5]=f2bf(a1.y*0.125f); t0[6]=f2bf(a1.z*0.125f); t0[7]=f2bf(a1.w*0.125f);
        t1[0]=f2bf(b0.x*0.125f); t1[1]=f2bf(b0.y*0.125f); t1[2]=f2bf(b0.z*0.125f); t1[3]=f2bf(b0.w*0.125f);
        t1[4]=f2bf(b1.x*0.125f); t1[5]=f2bf(b1.y*0.125f); t1[6]=f2bf(b1.z*0.125f); t1[7]=f2bf(b1.w*0.125f);
        qf0 = __builtin_bit_cast(bf16x8, t0);
        qf1 = __builtin_bit_cast(bf16x8, t1);
    }

    // ---- staging helpers (reg-staged: load early, convert+write late) ----
    const int krow = tid >> 3;               // 0..63 (key index in chunk)
    const int kd0  = (tid & 7) * 8;
    auto loadK = [&](int c0, float4& a, float4& bb) {
        const float* src = kbase + (size_t)(c0 + krow) * DH + kd0;
        a  = *(const float4*)(src);
        bb = *(const float4*)(src + 4);
    };
    auto writeK = [&](short* dst, const float4& a, const float4& bb) {
        s16x8 vv;
        vv[0]=f2bf(a.x);  vv[1]=f2bf(a.y);  vv[2]=f2bf(a.z);  vv[3]=f2bf(a.w);
        vv[4]=f2bf(bb.x); vv[5]=f2bf(bb.y); vv[6]=f2bf(bb.z); vv[7]=f2bf(bb.w);
        *(s16x8*)&dst[SW(krow, kd0)] = vv;
    };
    const int vr0 = (tid & 31) * 2;          // 0..62 (even key)
    const int vdg = tid >> 5;                // 0..15 (4 d's each)
    auto loadV = [&](int c0, float4& a, float4& bb) {
        const float* src = vbase + (size_t)(c0 + vr0) * DH + vdg * 4;
        a  = *(const float4*)(src);
        bb = *(const float4*)(src + DH);
    };
    auto writeVt = [&](short* dst, const float4& a, const float4& bb) {
        const float av[4] = {a.x, a.y, a.z, a.w};
        const float bv[4] = {bb.x, bb.y, bb.z, bb.w};
        int* dw = (int*)dst;
#pragma unroll
        for (int i = 0; i < 4; ++i) {
            const int d = vdg * 4 + i;
            dw[(d * 64 + (vr0 ^ ((d & 7) << 3))) >> 1] = (int)pack2(av[i], bv[i]);
        }
    };

    // prologue for pass A: chunk 0 into buffer 0
    float4 ka, kb;
    loadK(0, ka, kb);
    writeK(shK[0], ka, kb);
    __syncthreads();

    // ---------------- PASS A: row sumexp (fixed C=0), lane-local ----------------
    float lacc = 0.f;
    for (int t = 0; t < NCH; ++t) {
        const int cur = t & 1;
        if (t + 1 < NCH) loadK((t + 1) * 64, ka, kb);   // issue a chunk early
        __syncthreads();                                 // buf[cur] ready
        const short* K = shK[cur];
        const int c0 = t * 64;
        f32x4 s[4] = {{0,0,0,0},{0,0,0,0},{0,0,0,0},{0,0,0,0}};
#pragma unroll
        for (int ct = 0; ct < 4; ++ct) {
            const int kc = ct * 16 + l15;
            bf16x8 kf = ldfrag(&K[SW(kc, 8 * lg)]);
            s[ct] = __builtin_amdgcn_mfma_f32_16x16x32_bf16(kf, qf0, s[ct], 0, 0, 0);
            kf = ldfrag(&K[SW(kc, 32 + 8 * lg)]);
            s[ct] = __builtin_amdgcn_mfma_f32_16x16x32_bf16(kf, qf1, s[ct], 0, 0, 0);
        }
#pragma unroll
        for (int ct = 0; ct < 4; ++ct) {
            const unsigned mw = *(const unsigned*)&shMask[c0 + ct * 16 + lg * 4];
#pragma unroll
            for (int r = 0; r < 4; ++r)
                lacc += ((mw >> (8 * r)) & 1u) ? __expf(s[ct][r]) : 0.f;
        }
        if (t + 1 < NCH) writeK(shK[cur ^ 1], ka, kb);
    }
    lacc += __shfl_xor(lacc, 16);
    lacc += __shfl_xor(lacc, 32);
    const float lnInvl = -__logf(lacc);

    // ---------------- PASS B: recompute, write attn, PV accumulate ----------------
    f32x4 oacc[4] = {{0,0,0,0},{0,0,0,0},{0,0,0,0},{0,0,0,0}};
    float4 va, vb;
    loadK(0, ka, kb);
    loadV(0, va, vb);
    // all waves passed pass-A's last barrier; buf0 reads finished at t=30
    writeK(shK[0], ka, kb);
    writeVt(shVt[0], va, vb);

    float* const shPTw = shPT[w];
    for (int t = 0; t < NCH; ++t) {
        const int cur = t & 1;
        if (t + 1 < NCH) { loadK((t + 1) * 64, ka, kb); loadV((t + 1) * 64, va, vb); }
        __syncthreads();
        const short* K  = shK[cur];
        const short* Vt = shVt[cur];
        const int c0 = t * 64;

        // phase 1: all 4 score tiles (independent chains)
        f32x4 s[4] = {{0,0,0,0},{0,0,0,0},{0,0,0,0},{0,0,0,0}};
#pragma unroll
        for (int ct = 0; ct < 4; ++ct) {
            const int kc = ct * 16 + l15;
            bf16x8 kf = ldfrag(&K[SW(kc, 8 * lg)]);
            s[ct] = __builtin_amdgcn_mfma_f32_16x16x32_bf16(kf, qf0, s[ct], 0, 0, 0);
            kf = ldfrag(&K[SW(kc, 32 + 8 * lg)]);
            s[ct] = __builtin_amdgcn_mfma_f32_16x16x32_bf16(kf, qf1, s[ct], 0, 0, 0);
        }
        // phase 2: exp + mask; stash f32 P to per-wave LDS; pack bf16 p-quads
        s16x4 pf[4];
#pragma unroll
        for (int ct = 0; ct < 4; ++ct) {
            const unsigned mw = *(const unsigned*)&shMask[c0 + ct * 16 + lg * 4];
            f32x4 p;
#pragma unroll
            for (int r = 0; r < 4; ++r)
                p[r] = ((mw >> (8 * r)) & 1u) ? __expf(s[ct][r] + lnInvl) : 0.f;
            *(f32x4*)&shPTw[SWF(l15, ct * 16 + lg * 4)] = p;
            u32x2 pk;
            pk[0] = pack2(p[0], p[1]);
            pk[1] = pack2(p[2], p[3]);
            pf[ct] = __builtin_bit_cast(s16x4, pk);
        }
        // phase 2b: transposed full-line stores — 8 lanes x 16B = one whole
        // 128B line per row, 8 rows per instr. PLAIN stores (R16 experiment):
        // full-line writes should allocate-without-fetch in L2 and drain at
        // the fill-kernel rate; nt (R11) bypassed L2 and sustained only ~4.5.
#pragma unroll
        for (int st = 0; st < 4; ++st) {
            const int rowIdx = (lane >> 3) + (st >> 1) * 8;
            const int cm     = (lane & 7) * 4 + (st & 1) * 32;
            const f32x4 pv_ = *(const f32x4*)&shPTw[SWF(rowIdx, cm)];
            *(f32x4*)(attnbh + (size_t)(q0 + w * 16 + rowIdx) * S_LEN + c0 + cm) = pv_;
        }
        // phase 3: PV, 4 independent oacc chains x 4 k-quads (K=16 MFMA)
#pragma unroll
        for (int dt = 0; dt < 4; ++dt) {
#pragma unroll
            for (int ct = 0; ct < 4; ++ct) {
                const s16x4 af = *(const s16x4*)&Vt[SW(dt * 16 + l15, ct * 16 + 4 * lg)];
                oacc[dt] = __builtin_amdgcn_mfma_f32_16x16x16bf16_1k(af, pf[ct], oacc[dt], 0, 0, 0);
            }
        }
        if (t + 1 < NCH) { writeK(shK[cur ^ 1], ka, kb); writeVt(shVt[cur ^ 1], va, vb); }
    }

    // ---- epilogue: out[q][d]; nt (quarter-line scattered; plain would RFO) ----
    float* obase = out + ((size_t)bh * S_LEN + q0 + qrow) * DH;
#pragma unroll
    for (int dt = 0; dt < 4; ++dt)
        __builtin_nontemporal_store(oacc[dt], (f32x4*)(obase + dt * 16 + lg * 4));
}

extern "C" void kernel_launch(void* const* d_in, const int* in_sizes, int n_in,
                              void* d_out, int out_size, void* d_ws, size_t ws_size,
                              hipStream_t stream)
{
    const float* q    = (const float*)d_in[0];
    const float* k    = (const float*)d_in[1];
    const float* v    = (const float*)d_in[2];
    const int*   mask = (const int*)d_in[3];
    float* out  = (float*)d_out;
    float* attn = out + (size_t)2 * 16 * 2048 * 64;   // (out, attn) concatenated

    dim3 grid(S_LEN / QT, 2 * 16);   // 2D grid (x=qtile, y=bh) — pinned (R12)
    sdpa_kernel<<<grid, dim3(512), 0, stream>>>(q, k, v, mask, out, attn);
}